// Round 10
// baseline (148.917 us; speedup 1.0000x reference)
//
#include <hip/hip_runtime.h>
#include <cstddef>

#define NB 64
#define NQ 64
#define NK 8192
#define ND 64
#define KPB 256            // k per block, both MFMA kernels (4 waves x 64 k)
#define NSLICE (NK / KPB)  // 32 partial slices per b

typedef __attribute__((ext_vector_type(8))) short short8_t;
typedef __attribute__((ext_vector_type(4))) float float4_t;
typedef __attribute__((ext_vector_type(4))) unsigned short ushort4_t;

static __device__ __forceinline__ unsigned short f2bf(float f) {
    unsigned b = __float_as_uint(f);
    b += 0x7FFFu + ((b >> 16) & 1u);          // RNE
    return (unsigned short)(b >> 16);
}
static __device__ __forceinline__ float bf2f(unsigned short u) {
    return __uint_as_float(((unsigned)u) << 16);
}
static __device__ __forceinline__ void split8(const float* f, short8_t& hi, short8_t& lo) {
#pragma unroll
    for (int j = 0; j < 8; ++j) {
        const unsigned u = __float_as_uint(f[j]);
        hi[j] = (short)(u >> 16);
        const float lof = f[j] - __uint_as_float(u & 0xFFFF0000u);
        lo[j] = (short)(__float_as_uint(lof) >> 16);
    }
}

// ---------------------------------------------------------------------------
// Pass A: rowsum only. MFMA QK^T (bf16 hi/lo split) + inverted softmax,
// atomicAdd rowsum[b,q]. K loads software-pipelined across subtiles.
// ---------------------------------------------------------------------------
__global__ __launch_bounds__(256, 3) void k_qk_rowsum(
    const float* __restrict__ query,
    const float* __restrict__ key,
    float* __restrict__ rowsum)
{
    __shared__ alignas(16) unsigned short Qhi[64 * 72];
    __shared__ alignas(16) unsigned short Qlo[64 * 72];

    const int tid  = threadIdx.x;
    const int b    = blockIdx.y;
    const int k0   = blockIdx.x * KPB;
    const int lane = tid & 63;
    const int w    = tid >> 6;
    const int lq   = lane & 15;
    const int lg   = lane >> 4;

    // K subtile-0 preload (issued before Q staging; flies under it)
    float kf[16];
    {
        const float* kr = key + ((size_t)b * NK + k0 + w * 64 + lq) * ND + lg * 8;
        *reinterpret_cast<float4*>(kf)      = *reinterpret_cast<const float4*>(kr);
        *reinterpret_cast<float4*>(kf + 4)  = *reinterpret_cast<const float4*>(kr + 4);
        *reinterpret_cast<float4*>(kf + 8)  = *reinterpret_cast<const float4*>(kr + 32);
        *reinterpret_cast<float4*>(kf + 12) = *reinterpret_cast<const float4*>(kr + 36);
    }

    {
        const float* qb = query + (size_t)b * NQ * ND;
#pragma unroll
        for (int i = 0; i < 2; ++i) {
            const int o  = tid + 256 * i;
            const int q  = o >> 3;
            const int d0 = (o & 7) * 8;
            float f[8];
            *reinterpret_cast<float4*>(f)     = *reinterpret_cast<const float4*>(qb + q * ND + d0);
            *reinterpret_cast<float4*>(f + 4) = *reinterpret_cast<const float4*>(qb + q * ND + d0 + 4);
            short8_t h, l8;
            split8(f, h, l8);
            const int n    = q >> 4;
            const int l    = (q & 15) | (((d0 >> 3) & 3) << 4);
            const int dh   = d0 >> 5;
            const int base = l * 72 + n * 16 + dh * 8;
            *reinterpret_cast<short8_t*>(&Qhi[base]) = h;
            *reinterpret_cast<short8_t*>(&Qlo[base]) = l8;
        }
    }
    __syncthreads();

    short8_t bhi[4][2], blo[4][2];
#pragma unroll
    for (int n = 0; n < 4; ++n)
#pragma unroll
        for (int dh = 0; dh < 2; ++dh) {
            const int base = lane * 72 + n * 16 + dh * 8;
            bhi[n][dh] = *reinterpret_cast<const short8_t*>(&Qhi[base]);
            blo[n][dh] = *reinterpret_cast<const short8_t*>(&Qlo[base]);
        }

    float rsacc[4] = {0.f, 0.f, 0.f, 0.f};

#pragma unroll 1
    for (int s = 0; s < 4; ++s) {
        const int kbase = k0 + w * 64 + s * 16;

        short8_t ahi[2], alo[2];
        split8(kf, ahi[0], alo[0]);
        split8(kf + 8, ahi[1], alo[1]);

        if (s < 3) {   // issue next subtile's K loads
            const float* kr = key + ((size_t)b * NK + kbase + 16 + lq) * ND + lg * 8;
            *reinterpret_cast<float4*>(kf)      = *reinterpret_cast<const float4*>(kr);
            *reinterpret_cast<float4*>(kf + 4)  = *reinterpret_cast<const float4*>(kr + 4);
            *reinterpret_cast<float4*>(kf + 8)  = *reinterpret_cast<const float4*>(kr + 32);
            *reinterpret_cast<float4*>(kf + 12) = *reinterpret_cast<const float4*>(kr + 36);
        }

        float4_t acc[4];
#pragma unroll
        for (int n = 0; n < 4; ++n) acc[n] = (float4_t){0.f, 0.f, 0.f, 0.f};
#pragma unroll
        for (int n = 0; n < 4; ++n)
#pragma unroll
            for (int dh = 0; dh < 2; ++dh) {
                acc[n] = __builtin_amdgcn_mfma_f32_16x16x32_bf16(ahi[dh], bhi[n][dh], acc[n], 0, 0, 0);
                acc[n] = __builtin_amdgcn_mfma_f32_16x16x32_bf16(ahi[dh], blo[n][dh], acc[n], 0, 0, 0);
                acc[n] = __builtin_amdgcn_mfma_f32_16x16x32_bf16(alo[dh], bhi[n][dh], acc[n], 0, 0, 0);
            }

        float m[4], z[4];
#pragma unroll
        for (int r = 0; r < 4; ++r) {
            m[r] = fmaxf(fmaxf(acc[0][r], acc[1][r]), fmaxf(acc[2][r], acc[3][r]));
            m[r] = fmaxf(m[r], __shfl_xor(m[r], 1, 64));
            m[r] = fmaxf(m[r], __shfl_xor(m[r], 2, 64));
            m[r] = fmaxf(m[r], __shfl_xor(m[r], 4, 64));
            m[r] = fmaxf(m[r], __shfl_xor(m[r], 8, 64));
            z[r] = 0.f;
        }
#pragma unroll
        for (int n = 0; n < 4; ++n)
#pragma unroll
            for (int r = 0; r < 4; ++r) {
                acc[n][r] = __expf((acc[n][r] - m[r]) * 0.125f);
                z[r] += acc[n][r];
            }
#pragma unroll
        for (int r = 0; r < 4; ++r) {
            z[r] += __shfl_xor(z[r], 1, 64);
            z[r] += __shfl_xor(z[r], 2, 64);
            z[r] += __shfl_xor(z[r], 4, 64);
            z[r] += __shfl_xor(z[r], 8, 64);
            z[r] = 1.f / z[r];
        }
#pragma unroll
        for (int n = 0; n < 4; ++n) {
            float rs = 0.f;
#pragma unroll
            for (int r = 0; r < 4; ++r) rs += acc[n][r] * z[r];
            rs += __shfl_xor(rs, 16, 64);
            rs += __shfl_xor(rs, 32, 64);
            rsacc[n] += rs;
        }
    }

    if (lg == 0) {
#pragma unroll
        for (int n = 0; n < 4; ++n)
            atomicAdd(&rowsum[b * NQ + lq + 16 * n], rsacc[n]);
    }
}

// ---------------------------------------------------------------------------
// Pass B: recompute QK^T via MFMA (K pipelined), pack FINAL bf16 p into LDS;
// PV via MFMA with V staged row-major fp32 [64][68] + column-XOR swizzle
// (stores balanced across 32 banks; scalar reads 2-way = free), split to
// bf16 in regs; deterministic per-block partials; attn written LAST as a
// fully-coalesced sweep from pL (1KB-per-instruction row writes) so no
// barrier ever drains the 134 MB attn stream.
// LDS: SH 33 KB (Q frags / p tile) + Vs 17 KB + rsL = 51 KB -> 3 blk/CU.
// ---------------------------------------------------------------------------
__global__ __launch_bounds__(256, 3) void k_attn_pv_mfma(
    const float* __restrict__ query,
    const float* __restrict__ key,
    const float* __restrict__ value,
    const float* __restrict__ rowsum,
    float* __restrict__ attn,
    float* __restrict__ partials)
{
    __shared__ alignas(16) unsigned short SH[64 * 264];    // Q frags, then p tile
    __shared__ alignas(16) float Vs[64 * 68];              // [kk][d ^ swz] fp32
    __shared__ float rsL[64];

    const int tid  = threadIdx.x;
    const int b    = blockIdx.y;
    const int k0   = blockIdx.x * KPB;
    const int lane = tid & 63;
    const int w    = tid >> 6;
    const int lq   = lane & 15;
    const int lg   = lane >> 4;

    unsigned short* Qhi = SH;
    unsigned short* Qlo = SH + 64 * 72;

    // ---- V chunk-0 prefetch (in flight during Q staging + QK^T phase)
    const int vk4 = (tid >> 4) * 4;          // rows this thread stages
    const int vd4 = (tid & 15) * 4;          // col quad
    const float4* vg = reinterpret_cast<const float4*>(value + ((size_t)b * NK + k0) * ND);
    float4 vt[4];
#pragma unroll
    for (int r = 0; r < 4; ++r)
        vt[r] = vg[(vk4 + r) * 16 + (vd4 >> 2)];

    // ---- K subtile-0 preload
    float kf[16];
    {
        const float* kr = key + ((size_t)b * NK + k0 + w * 64 + lq) * ND + lg * 8;
        *reinterpret_cast<float4*>(kf)      = *reinterpret_cast<const float4*>(kr);
        *reinterpret_cast<float4*>(kf + 4)  = *reinterpret_cast<const float4*>(kr + 4);
        *reinterpret_cast<float4*>(kf + 8)  = *reinterpret_cast<const float4*>(kr + 32);
        *reinterpret_cast<float4*>(kf + 12) = *reinterpret_cast<const float4*>(kr + 36);
    }

    // ---- stage Q fragments hi/lo
    {
        const float* qb = query + (size_t)b * NQ * ND;
#pragma unroll
        for (int i = 0; i < 2; ++i) {
            const int o  = tid + 256 * i;
            const int q  = o >> 3;
            const int d0 = (o & 7) * 8;
            float f[8];
            *reinterpret_cast<float4*>(f)     = *reinterpret_cast<const float4*>(qb + q * ND + d0);
            *reinterpret_cast<float4*>(f + 4) = *reinterpret_cast<const float4*>(qb + q * ND + d0 + 4);
            short8_t h, l8;
            split8(f, h, l8);
            const int n    = q >> 4;
            const int l    = (q & 15) | (((d0 >> 3) & 3) << 4);
            const int dh   = d0 >> 5;
            const int base = l * 72 + n * 16 + dh * 8;
            *reinterpret_cast<short8_t*>(&Qhi[base]) = h;
            *reinterpret_cast<short8_t*>(&Qlo[base]) = l8;
        }
    }
    if (tid < 64) rsL[tid] = 1.f / (rowsum[b * NQ + tid] + 1e-8f);
    __syncthreads();

    short8_t bhi[4][2], blo[4][2];
#pragma unroll
    for (int n = 0; n < 4; ++n)
#pragma unroll
        for (int dh = 0; dh < 2; ++dh) {
            const int base = lane * 72 + n * 16 + dh * 8;
            bhi[n][dh] = *reinterpret_cast<const short8_t*>(&Qhi[base]);
            blo[n][dh] = *reinterpret_cast<const short8_t*>(&Qlo[base]);
        }
    __syncthreads();                       // Q frags in regs -> SH reusable

    unsigned short* pL = SH;               // p tile [64 q][264 pitch], cols=256 k
    float invr[4];
#pragma unroll
    for (int n = 0; n < 4; ++n) invr[n] = rsL[16 * n + lq];

    // ---- QK^T + softmax + p pack (bf16 FINAL values), K pipelined
#pragma unroll 1
    for (int s = 0; s < 4; ++s) {
        const int kbase = k0 + w * 64 + s * 16;

        short8_t ahi[2], alo[2];
        split8(kf, ahi[0], alo[0]);
        split8(kf + 8, ahi[1], alo[1]);

        if (s < 3) {
            const float* kr = key + ((size_t)b * NK + kbase + 16 + lq) * ND + lg * 8;
            *reinterpret_cast<float4*>(kf)      = *reinterpret_cast<const float4*>(kr);
            *reinterpret_cast<float4*>(kf + 4)  = *reinterpret_cast<const float4*>(kr + 4);
            *reinterpret_cast<float4*>(kf + 8)  = *reinterpret_cast<const float4*>(kr + 32);
            *reinterpret_cast<float4*>(kf + 12) = *reinterpret_cast<const float4*>(kr + 36);
        }

        float4_t acc[4];
#pragma unroll
        for (int n = 0; n < 4; ++n) acc[n] = (float4_t){0.f, 0.f, 0.f, 0.f};
#pragma unroll
        for (int n = 0; n < 4; ++n)
#pragma unroll
            for (int dh = 0; dh < 2; ++dh) {
                acc[n] = __builtin_amdgcn_mfma_f32_16x16x32_bf16(ahi[dh], bhi[n][dh], acc[n], 0, 0, 0);
                acc[n] = __builtin_amdgcn_mfma_f32_16x16x32_bf16(ahi[dh], blo[n][dh], acc[n], 0, 0, 0);
                acc[n] = __builtin_amdgcn_mfma_f32_16x16x32_bf16(alo[dh], bhi[n][dh], acc[n], 0, 0, 0);
            }

        float m[4], z[4];
#pragma unroll
        for (int r = 0; r < 4; ++r) {
            m[r] = fmaxf(fmaxf(acc[0][r], acc[1][r]), fmaxf(acc[2][r], acc[3][r]));
            m[r] = fmaxf(m[r], __shfl_xor(m[r], 1, 64));
            m[r] = fmaxf(m[r], __shfl_xor(m[r], 2, 64));
            m[r] = fmaxf(m[r], __shfl_xor(m[r], 4, 64));
            m[r] = fmaxf(m[r], __shfl_xor(m[r], 8, 64));
            z[r] = 0.f;
        }
#pragma unroll
        for (int n = 0; n < 4; ++n)
#pragma unroll
            for (int r = 0; r < 4; ++r) {
                acc[n][r] = __expf((acc[n][r] - m[r]) * 0.125f);
                z[r] += acc[n][r];
            }
#pragma unroll
        for (int r = 0; r < 4; ++r) {
            z[r] += __shfl_xor(z[r], 1, 64);
            z[r] += __shfl_xor(z[r], 2, 64);
            z[r] += __shfl_xor(z[r], 4, 64);
            z[r] += __shfl_xor(z[r], 8, 64);
            z[r] = 1.f / z[r];
        }

#pragma unroll
        for (int n = 0; n < 4; ++n) {
            ushort4_t u;
#pragma unroll
            for (int r = 0; r < 4; ++r)
                u[r] = f2bf(acc[n][r] * z[r] * invr[n]);   // FINAL attn value
            *reinterpret_cast<ushort4_t*>(
                &pL[(16 * n + lq) * 264 + (kbase - k0) + lg * 4]) = u;
        }
    }
    __syncthreads();   // full p tile packed

    // ---- PV via MFMA over 4 chunks of 64 k
    float4_t oacc[4];
#pragma unroll
    for (int n = 0; n < 4; ++n) oacc[n] = (float4_t){0.f, 0.f, 0.f, 0.f};

#pragma unroll 1
    for (int c = 0; c < 4; ++c) {
        // stage Vs row-major with column-group XOR swizzle
#pragma unroll
        for (int r = 0; r < 4; ++r) {
            const int row = vk4 + r;
            const int xr  = ((row >> 3) & 3) << 3;
            *reinterpret_cast<float4*>(&Vs[row * 68 + (vd4 ^ xr)]) = vt[r];
        }
        if (c < 3) {   // prefetch next V chunk; flies under this chunk's MFMAs
#pragma unroll
            for (int r = 0; r < 4; ++r)
                vt[r] = vg[((c + 1) * 64 + vk4 + r) * 16 + (vd4 >> 2)];
        }
        __syncthreads();   // Vs ready

#pragma unroll
        for (int h = 0; h < 2; ++h) {
            float vf[8];
            const int dsw = (16 * w + lq) ^ (lg << 3);
#pragma unroll
            for (int j = 0; j < 8; ++j)
                vf[j] = Vs[(h * 32 + lg * 8 + j) * 68 + dsw];
            short8_t vhi, vlo;
            split8(vf, vhi, vlo);
#pragma unroll
            for (int n = 0; n < 4; ++n) {
                const short8_t pa = *reinterpret_cast<const short8_t*>(
                    &pL[(16 * n + lq) * 264 + c * 64 + h * 32 + lg * 8]);
                oacc[n] = __builtin_amdgcn_mfma_f32_16x16x32_bf16(pa, vhi, oacc[n], 0, 0, 0);
                oacc[n] = __builtin_amdgcn_mfma_f32_16x16x32_bf16(pa, vlo, oacc[n], 0, 0, 0);
            }
        }
        __syncthreads();   // Vs consumed before next chunk's stores
    }

    // ---- partials: partial[b][slice][q][d]; row q = 16n+4lg+r, col d = 16w+lq
    float* pb = partials + ((size_t)(b * NSLICE + blockIdx.x)) * (NQ * ND);
#pragma unroll
    for (int n = 0; n < 4; ++n)
#pragma unroll
        for (int r = 0; r < 4; ++r)
            pb[(16 * n + 4 * lg + r) * ND + 16 * w + lq] = oacc[n][r];

    // ---- attn sweep: wave-contiguous 1KB row writes from pL (fire-and-forget)
    {
        const int cl = tid & 63;
#pragma unroll
        for (int qq = 0; qq < 16; ++qq) {
            const int row = qq * 4 + w;
            const ushort4_t u = *reinterpret_cast<const ushort4_t*>(
                &pL[row * 264 + cl * 4]);
            float o[4];
#pragma unroll
            for (int e = 0; e < 4; ++e) o[e] = bf2f(u[e]);
            *reinterpret_cast<float4*>(attn +
                ((size_t)(b * NQ + row)) * NK + k0 + cl * 4) = *reinterpret_cast<float4*>(o);
        }
    }
}

// ---------------------------------------------------------------------------
// Reduce: out[b,q,d] = sum over 32 slices of partial[b][s][q][d].
// ---------------------------------------------------------------------------
__global__ __launch_bounds__(256) void k_reduce_out(
    const float* __restrict__ partials,
    float* __restrict__ out)
{
    const int b   = blockIdx.y;
    const int idx = blockIdx.x * 256 + threadIdx.x;    // 0..1023 float4 per b
    const float4* pb = reinterpret_cast<const float4*>(partials + (size_t)b * NSLICE * NQ * ND);
    float4 sum = make_float4(0.f, 0.f, 0.f, 0.f);
#pragma unroll
    for (int s = 0; s < NSLICE; ++s) {
        const float4 v = pb[(size_t)s * (NQ * ND / 4) + idx];
        sum.x += v.x; sum.y += v.y; sum.z += v.z; sum.w += v.w;
    }
    reinterpret_cast<float4*>(out + (size_t)b * NQ * ND)[idx] = sum;
}

extern "C" void kernel_launch(void* const* d_in, const int* in_sizes, int n_in,
                              void* d_out, int out_size, void* d_ws, size_t ws_size,
                              hipStream_t stream) {
    const float* query = (const float*)d_in[0];
    const float* key   = (const float*)d_in[1];
    const float* value = (const float*)d_in[2];

    float* out  = (float*)d_out;                        // [B,Q,D]
    float* attn = (float*)d_out + (size_t)NB * NQ * ND; // [B,Q,K]
    float* rowsum   = (float*)d_ws;                     // 16 KB pad
    float* partials = (float*)((char*)d_ws + 16384);    // 33.5 MB

    hipMemsetAsync(rowsum, 0, (size_t)NB * NQ * sizeof(float), stream);

    dim3 g(NK / KPB, NB);
    k_qk_rowsum<<<g, 256, 0, stream>>>(query, key, rowsum);
    k_attn_pv_mfma<<<g, 256, 0, stream>>>(query, key, value, rowsum, attn, partials);
    k_reduce_out<<<dim3(4, NB), 256, 0, stream>>>(partials, out);
}

// Round 11
// 119.318 us; speedup vs baseline: 1.2481x; 1.2481x over previous
//
#include <hip/hip_runtime.h>
#include <cstddef>

#define NB 64
#define NQ 64
#define NK 8192
#define ND 64
#define KPB 256            // pass A: k per block (4 waves x 64 k)
#define KSL 512            // pass B: k per block (4 half-tiles of 128)
#define NSLICE (NK / KSL)  // 16 partial slices per b

typedef __attribute__((ext_vector_type(8))) short short8_t;
typedef __attribute__((ext_vector_type(8))) unsigned short ushort8_t;
typedef __attribute__((ext_vector_type(4))) unsigned short ushort4_t;
typedef __attribute__((ext_vector_type(4))) float float4_t;

static __device__ __forceinline__ unsigned short f2bf(float f) {
    unsigned b = __float_as_uint(f);
    b += 0x7FFFu + ((b >> 16) & 1u);          // RNE
    return (unsigned short)(b >> 16);
}
static __device__ __forceinline__ float bf2f(unsigned short u) {
    return __uint_as_float(((unsigned)u) << 16);
}
static __device__ __forceinline__ void split8(const float* f, short8_t& hi, short8_t& lo) {
#pragma unroll
    for (int j = 0; j < 8; ++j) {
        const unsigned u = __float_as_uint(f[j]);
        hi[j] = (short)(u >> 16);
        const float lof = f[j] - __uint_as_float(u & 0xFFFF0000u);
        lo[j] = (short)(__float_as_uint(lof) >> 16);
    }
}

// ---------------------------------------------------------------------------
// Pass A: MFMA QK^T (bf16 hi/lo 3-term split) + inverted softmax.
// Stores UNNORMALIZED p (bf16) to ws, PRE-SWIZZLED within each 128-k half
// (16B slot index ^= row&7) so pass B stages LDS linearly and reads MFMA
// A-frags 2-way-conflict-free. rowsum accumulated from the ROUNDED values.
// p funneled through LDS -> coalesced 512B-row global writes.
// ---------------------------------------------------------------------------
__global__ __launch_bounds__(256, 3) void k_qk_p(
    const float* __restrict__ query,
    const float* __restrict__ key,
    unsigned short* __restrict__ pstore,
    float* __restrict__ rowsum)
{
    __shared__ alignas(16) unsigned short SH[64 * 264];  // Q frags, then p tile
    unsigned short* Qhi = SH;
    unsigned short* Qlo = SH + 64 * 72;

    const int tid  = threadIdx.x;
    const int b    = blockIdx.y;
    const int k0   = blockIdx.x * KPB;
    const int lane = tid & 63;
    const int w    = tid >> 6;
    const int lq   = lane & 15;
    const int lg   = lane >> 4;

    // K subtile-0 preload (flies under Q staging)
    float kf[16];
    {
        const float* kr = key + ((size_t)b * NK + k0 + w * 64 + lq) * ND + lg * 8;
        *reinterpret_cast<float4*>(kf)      = *reinterpret_cast<const float4*>(kr);
        *reinterpret_cast<float4*>(kf + 4)  = *reinterpret_cast<const float4*>(kr + 4);
        *reinterpret_cast<float4*>(kf + 8)  = *reinterpret_cast<const float4*>(kr + 32);
        *reinterpret_cast<float4*>(kf + 12) = *reinterpret_cast<const float4*>(kr + 36);
    }

    // stage Q fragments hi/lo
    {
        const float* qb = query + (size_t)b * NQ * ND;
#pragma unroll
        for (int i = 0; i < 2; ++i) {
            const int o  = tid + 256 * i;
            const int q  = o >> 3;
            const int d0 = (o & 7) * 8;
            float f[8];
            *reinterpret_cast<float4*>(f)     = *reinterpret_cast<const float4*>(qb + q * ND + d0);
            *reinterpret_cast<float4*>(f + 4) = *reinterpret_cast<const float4*>(qb + q * ND + d0 + 4);
            short8_t h, l8;
            split8(f, h, l8);
            const int n    = q >> 4;
            const int l    = (q & 15) | (((d0 >> 3) & 3) << 4);
            const int dh   = d0 >> 5;
            const int base = l * 72 + n * 16 + dh * 8;
            *reinterpret_cast<short8_t*>(&Qhi[base]) = h;
            *reinterpret_cast<short8_t*>(&Qlo[base]) = l8;
        }
    }
    __syncthreads();

    short8_t bhi[4][2], blo[4][2];
#pragma unroll
    for (int n = 0; n < 4; ++n)
#pragma unroll
        for (int dh = 0; dh < 2; ++dh) {
            const int base = lane * 72 + n * 16 + dh * 8;
            bhi[n][dh] = *reinterpret_cast<const short8_t*>(&Qhi[base]);
            blo[n][dh] = *reinterpret_cast<const short8_t*>(&Qlo[base]);
        }
    __syncthreads();                       // Q frags in regs -> SH reusable

    unsigned short* pL = SH;               // p tile [64 q][264 pitch]
    float rsacc[4] = {0.f, 0.f, 0.f, 0.f};

#pragma unroll 1
    for (int s = 0; s < 4; ++s) {
        const int kbase = k0 + w * 64 + s * 16;

        short8_t ahi[2], alo[2];
        split8(kf, ahi[0], alo[0]);
        split8(kf + 8, ahi[1], alo[1]);

        if (s < 3) {   // pipeline next subtile's K loads
            const float* kr = key + ((size_t)b * NK + kbase + 16 + lq) * ND + lg * 8;
            *reinterpret_cast<float4*>(kf)      = *reinterpret_cast<const float4*>(kr);
            *reinterpret_cast<float4*>(kf + 4)  = *reinterpret_cast<const float4*>(kr + 4);
            *reinterpret_cast<float4*>(kf + 8)  = *reinterpret_cast<const float4*>(kr + 32);
            *reinterpret_cast<float4*>(kf + 12) = *reinterpret_cast<const float4*>(kr + 36);
        }

        float4_t acc[4];
#pragma unroll
        for (int n = 0; n < 4; ++n) acc[n] = (float4_t){0.f, 0.f, 0.f, 0.f};
#pragma unroll
        for (int n = 0; n < 4; ++n)
#pragma unroll
            for (int dh = 0; dh < 2; ++dh) {
                acc[n] = __builtin_amdgcn_mfma_f32_16x16x32_bf16(ahi[dh], bhi[n][dh], acc[n], 0, 0, 0);
                acc[n] = __builtin_amdgcn_mfma_f32_16x16x32_bf16(ahi[dh], blo[n][dh], acc[n], 0, 0, 0);
                acc[n] = __builtin_amdgcn_mfma_f32_16x16x32_bf16(alo[dh], bhi[n][dh], acc[n], 0, 0, 0);
            }

        float m[4], z[4];
#pragma unroll
        for (int r = 0; r < 4; ++r) {
            m[r] = fmaxf(fmaxf(acc[0][r], acc[1][r]), fmaxf(acc[2][r], acc[3][r]));
            m[r] = fmaxf(m[r], __shfl_xor(m[r], 1, 64));
            m[r] = fmaxf(m[r], __shfl_xor(m[r], 2, 64));
            m[r] = fmaxf(m[r], __shfl_xor(m[r], 4, 64));
            m[r] = fmaxf(m[r], __shfl_xor(m[r], 8, 64));
            z[r] = 0.f;
        }
#pragma unroll
        for (int n = 0; n < 4; ++n)
#pragma unroll
            for (int r = 0; r < 4; ++r) {
                acc[n][r] = __expf((acc[n][r] - m[r]) * 0.125f);   // 1/sqrt(64) folded
                z[r] += acc[n][r];
            }
#pragma unroll
        for (int r = 0; r < 4; ++r) {
            z[r] += __shfl_xor(z[r], 1, 64);
            z[r] += __shfl_xor(z[r], 2, 64);
            z[r] += __shfl_xor(z[r], 4, 64);
            z[r] += __shfl_xor(z[r], 8, 64);
            z[r] = 1.f / z[r];
        }

#pragma unroll
        for (int n = 0; n < 4; ++n) {
            ushort4_t u;
            float rs = 0.f;
#pragma unroll
            for (int r = 0; r < 4; ++r) {
                u[r] = f2bf(acc[n][r] * z[r]);    // UNNORMALIZED p, bf16
                rs += bf2f(u[r]);                 // rowsum from rounded values
            }
            *reinterpret_cast<ushort4_t*>(
                &pL[(16 * n + lq) * 264 + w * 64 + s * 16 + lg * 4]) = u;
            rs += __shfl_xor(rs, 16, 64);
            rs += __shfl_xor(rs, 32, 64);
            rsacc[n] += rs;
        }
    }

    if (lg == 0) {
#pragma unroll
        for (int n = 0; n < 4; ++n)
            atomicAdd(&rowsum[b * NQ + lq + 16 * n], rsacc[n]);
    }
    __syncthreads();   // pL complete

    // ---- coalesced sweep: pL -> pstore, swizzled within each 128-k half:
    // phys 16B-slot = logical slot ^ (row&7). Wave writes full 512B rows.
    {
        const int cl = tid & 63;
#pragma unroll
        for (int t = 0; t < 16; ++t) {
            const int row = t * 4 + w;
            const ushort4_t u = *reinterpret_cast<const ushort4_t*>(&pL[row * 264 + cl * 4]);
            const int c      = cl * 4;            // u16 col 0..252
            const int half   = c >> 7;
            const int slot   = (c & 127) >> 3;    // logical 16B slot in half
            const int sub    = (c >> 2) & 1;
            const int sp     = slot ^ (row & 7);  // physical slot
            *reinterpret_cast<ushort4_t*>(pstore +
                ((size_t)(b * NQ + row)) * NK + k0 + half * 128 + sp * 8 + sub * 4) = u;
        }
    }
}

// ---------------------------------------------------------------------------
// Pass B: pure streaming. Per (b, 512-k tile), 4 half-tiles of 128 k:
// load swizzled bf16 p (linear, coalesced) + V, scale p by 1/(rowsum+eps),
// write FINAL fp32 attn (col de-swizzled), stage p (linear) + V (bf16) in
// LDS, PV via MFMA. A-frag reads land 2-way-conflict-free via the global
// pre-swizzle. T14: next half-tile's loads issued before PV. Partials
// (deterministic) or atomicAdd fallback.
// LDS: pL 16KB + Vs 17KB -> 4 blocks/CU. ~30 live VGPRs -> no spill.
// ---------------------------------------------------------------------------
template<bool PART>
__global__ __launch_bounds__(256, 4) void k_scale_pv(
    const unsigned short* __restrict__ psrc,
    const float* __restrict__ value,
    const float* __restrict__ rowsum,
    float* __restrict__ attn,
    float* __restrict__ dst)     // partials if PART else out
{
    __shared__ alignas(16) unsigned short pLu[64 * 128];   // linear swizzled image
    __shared__ alignas(16) unsigned short Vsu[128 * 68];   // [k][d] bf16
    __shared__ float rsL[NQ];

    const int tid  = threadIdx.x;
    const int b    = blockIdx.y;
    const int ks   = blockIdx.x;
    const int k0   = ks * KSL;
    const int lane = tid & 63;
    const int w    = tid >> 6;
    const int lq   = lane & 15;
    const int lg   = lane >> 4;

    if (tid < NQ) rsL[tid] = 1.f / (rowsum[b * NQ + tid] + 1e-8f);

    const unsigned short* pg = psrc + (size_t)b * NQ * NK;
    const float4* vg = reinterpret_cast<const float4*>(value + ((size_t)b * NK + k0) * ND);

    // prologue: half-tile 0 loads
    ushort8_t rp[4];
    float4 rv[8];
#pragma unroll
    for (int i = 0; i < 4; ++i) {
        const int idx = tid + 256 * i;
        rp[i] = *reinterpret_cast<const ushort8_t*>(
            &pg[(size_t)(idx >> 4) * NK + k0 + (idx & 15) * 8]);
    }
#pragma unroll
    for (int i = 0; i < 8; ++i) rv[i] = vg[tid + 256 * i];

    float4_t oacc[4];
#pragma unroll
    for (int n = 0; n < 4; ++n) oacc[n] = (float4_t){0.f, 0.f, 0.f, 0.f};

#pragma unroll 1
    for (int ht = 0; ht < 4; ++ht) {
        __syncthreads();   // prev PV done (ht=0: rsL visible)

        // ---- consume regs: attn write (de-swizzled col) + pL/Vs stage
#pragma unroll
        for (int i = 0; i < 4; ++i) {
            const int idx  = tid + 256 * i;
            const int row  = idx >> 4;
            const int sl   = idx & 15;                 // physical slot
            const int slog = sl ^ (row & 7);           // logical slot
            const float iv = rsL[row];
            float f[8];
            ushort8_t u;
#pragma unroll
            for (int j = 0; j < 8; ++j) {
                f[j] = bf2f(rp[i][j]) * iv;            // FINAL attn value, fp32
                u[j] = f2bf(f[j]);                     // bf16 for PV MFMA
            }
            float* ap = attn + ((size_t)(b * NQ + row)) * NK + k0 + ht * 128 + slog * 8;
            *reinterpret_cast<float4*>(ap)     = *reinterpret_cast<float4*>(f);
            *reinterpret_cast<float4*>(ap + 4) = *reinterpret_cast<float4*>(f + 4);
            *reinterpret_cast<ushort8_t*>(&pLu[idx * 8]) = u;   // linear
        }
#pragma unroll
        for (int i = 0; i < 8; ++i) {
            const int idx = tid + 256 * i;
            ushort4_t v4;
            v4[0] = f2bf(rv[i].x); v4[1] = f2bf(rv[i].y);
            v4[2] = f2bf(rv[i].z); v4[3] = f2bf(rv[i].w);
            *reinterpret_cast<ushort4_t*>(&Vsu[(idx >> 4) * 68 + (idx & 15) * 4]) = v4;
        }

        // ---- T14: issue next half-tile's loads (fly under PV)
        if (ht < 3) {
            const int kn = k0 + (ht + 1) * 128;
#pragma unroll
            for (int i = 0; i < 4; ++i) {
                const int idx = tid + 256 * i;
                rp[i] = *reinterpret_cast<const ushort8_t*>(
                    &pg[(size_t)(idx >> 4) * NK + kn + (idx & 15) * 8]);
            }
#pragma unroll
            for (int i = 0; i < 8; ++i)
                rv[i] = vg[(ht + 1) * 2048 + tid + 256 * i];
        }
        __syncthreads();   // LDS ready

        // ---- PV via MFMA: wave w owns d strip [16w,16w+16)
#pragma unroll
        for (int h = 0; h < 4; ++h) {
            short8_t vb;
#pragma unroll
            for (int j = 0; j < 8; ++j)
                vb[j] = (short)Vsu[(h * 32 + lg * 8 + j) * 68 + 16 * w + lq];
#pragma unroll
            for (int n = 0; n < 4; ++n) {
                const short8_t pa = *reinterpret_cast<const short8_t*>(
                    &pLu[(16 * n + lq) * 128 + (((h * 4 + lg) ^ (lq & 7)) * 8)]);
                oacc[n] = __builtin_amdgcn_mfma_f32_16x16x32_bf16(pa, vb, oacc[n], 0, 0, 0);
            }
        }
    }

    // ---- epilogue: D row q = 16n+4lg+r, col d = 16w+lq
    if (PART) {
        float* pb = dst + ((size_t)(b * NSLICE + ks)) * (NQ * ND);
#pragma unroll
        for (int n = 0; n < 4; ++n)
#pragma unroll
            for (int r = 0; r < 4; ++r)
                pb[(16 * n + 4 * lg + r) * ND + 16 * w + lq] = oacc[n][r];
    } else {
#pragma unroll
        for (int n = 0; n < 4; ++n)
#pragma unroll
            for (int r = 0; r < 4; ++r)
                atomicAdd(dst + ((size_t)(b * NQ + 16 * n + 4 * lg + r)) * ND + 16 * w + lq,
                          oacc[n][r]);
    }
}

// ---------------------------------------------------------------------------
// Reduce: out[b,q,d] = sum over 16 slices.
// ---------------------------------------------------------------------------
__global__ __launch_bounds__(256) void k_reduce_out(
    const float* __restrict__ partials,
    float* __restrict__ out)
{
    const int b   = blockIdx.y;
    const int idx = blockIdx.x * 256 + threadIdx.x;    // 0..1023 float4 per b
    const float4* pb = reinterpret_cast<const float4*>(partials + (size_t)b * NSLICE * NQ * ND);
    float4 sum = make_float4(0.f, 0.f, 0.f, 0.f);
#pragma unroll
    for (int s = 0; s < NSLICE; ++s) {
        const float4 v = pb[(size_t)s * (NQ * ND / 4) + idx];
        sum.x += v.x; sum.y += v.y; sum.z += v.z; sum.w += v.w;
    }
    reinterpret_cast<float4*>(out + (size_t)b * NQ * ND)[idx] = sum;
}

extern "C" void kernel_launch(void* const* d_in, const int* in_sizes, int n_in,
                              void* d_out, int out_size, void* d_ws, size_t ws_size,
                              hipStream_t stream) {
    const float* query = (const float*)d_in[0];
    const float* key   = (const float*)d_in[1];
    const float* value = (const float*)d_in[2];

    float* out  = (float*)d_out;                        // [B,Q,D]
    float* attn = (float*)d_out + (size_t)NB * NQ * ND; // [B,Q,K]

    const size_t PB_BYTES   = (size_t)NB * NQ * NK * sizeof(unsigned short); // 64 MiB
    const size_t PART_BYTES = (size_t)NB * NSLICE * NQ * ND * sizeof(float); // 16 MiB

    float* rowsum = (float*)d_ws;                               // 16 KB pad
    unsigned short* pbuf = (unsigned short*)((char*)d_ws + 16384);
    float* partials = (float*)((char*)d_ws + 16384 + PB_BYTES);
    const bool part = ws_size >= 16384 + PB_BYTES + PART_BYTES;

    hipMemsetAsync(rowsum, 0, (size_t)NB * NQ * sizeof(float), stream);
    if (!part)
        hipMemsetAsync(out, 0, (size_t)NB * NQ * ND * sizeof(float), stream);

    dim3 gA(NK / KPB, NB);
    k_qk_p<<<gA, 256, 0, stream>>>(query, key, pbuf, rowsum);

    dim3 gB(NK / KSL, NB);
    if (part) {
        k_scale_pv<true><<<gB, 256, 0, stream>>>(pbuf, value, rowsum, attn, partials);
        k_reduce_out<<<dim3(4, NB), 256, 0, stream>>>(partials, out);
    } else {
        k_scale_pv<false><<<gB, 256, 0, stream>>>(pbuf, value, rowsum, attn, out);
    }
}